// Round 1
// baseline (392.331 us; speedup 1.0000x reference)
//
#include <hip/hip_runtime.h>
#include <hip/hip_bf16.h>

// Shapes (fixed by the problem)
constexpr int CB = 4, CS = 2048, CD = 768, CH = 4, CDH = 192;
constexpr int CM = CB * CS;  // 8192 rows

typedef float f32x4 __attribute__((ext_vector_type(4)));
typedef float fx4 __attribute__((ext_vector_type(4)));
typedef __bf16 bx8 __attribute__((ext_vector_type(8)));
typedef unsigned short u16;
typedef u16 u16x8 __attribute__((ext_vector_type(8)));
typedef u16 u16x4 __attribute__((ext_vector_type(4)));

static __device__ __forceinline__ u16 f32_bf16(float f) {
  unsigned u = __builtin_bit_cast(unsigned, f);
  u += 0x7FFFu + ((u >> 16) & 1u);
  return (u16)(u >> 16);
}

static __device__ __forceinline__ f32x4 mfma16(bx8 a, bx8 b, f32x4 c) {
  return __builtin_amdgcn_mfma_f32_16x16x32_bf16(a, b, c, 0, 0, 0);
}

// ---------------------------------------------------------------- convert
__global__ void __launch_bounds__(256) convert_all(
    const float* __restrict__ x, const float* __restrict__ wq,
    const float* __restrict__ wk, const float* __restrict__ wv,
    const float* __restrict__ wo, u16* __restrict__ xb, u16* __restrict__ wqb,
    u16* __restrict__ wkb, u16* __restrict__ wvb, u16* __restrict__ wob) {
  const float* srcs[5] = {x, wq, wk, wv, wo};
  u16* dsts[5] = {xb, wqb, wkb, wvb, wob};
  const int n4s[5] = {CM * CD / 4, CD * CD / 4, CD * CD / 4, CD * CD / 4,
                      CD * CD / 4};
  const int gsz = gridDim.x * blockDim.x;
  const int gid = blockIdx.x * blockDim.x + threadIdx.x;
#pragma unroll
  for (int sg = 0; sg < 5; ++sg) {
    const fx4* src = (const fx4*)srcs[sg];
    u16* dst = dsts[sg];
    const int n4 = n4s[sg];
    for (int i = gid; i < n4; i += gsz) {
      fx4 v = src[i];
      u16x4 o;
      o[0] = f32_bf16(v[0]);
      o[1] = f32_bf16(v[1]);
      o[2] = f32_bf16(v[2]);
      o[3] = f32_bf16(v[3]);
      *(u16x4*)&dst[(size_t)i * 4] = o;
    }
  }
}

// ---------------------------------------------------------------- GEMM
// C[M,N] = A[M,K] @ B[N,K]^T ; A,B bf16 row-major. 128x128 tile, BK=64,
// 4 waves in 2x2, each wave 64x64 = 4x4 frags of 16x16x32.
template <bool OUT_BF16>
__global__ void __launch_bounds__(256) gemm_bt(
    const u16* __restrict__ A, const u16* __restrict__ Bw0,
    const u16* __restrict__ Bw1, const u16* __restrict__ Bw2,
    void* __restrict__ C0, void* __restrict__ C1, void* __restrict__ C2,
    int M, int N, int K) {
  constexpr int LDK = 72;  // padded: 16B slot = (9*row+c)%8 -> uniform
  __shared__ u16 As[128][LDK];
  __shared__ u16 Bs[128][LDK];
  const int z = blockIdx.z;
  const u16* Bw = (z == 0) ? Bw0 : ((z == 1) ? Bw1 : Bw2);
  void* Cv = (z == 0) ? C0 : ((z == 1) ? C1 : C2);
  const int m0 = blockIdx.x * 128;
  const int n0 = blockIdx.y * 128;
  const int tid = threadIdx.x;
  const int wave = tid >> 6, lane = tid & 63;
  const int wr = wave >> 1, wc = wave & 1;
  const int lr = lane & 15, lhi = lane >> 4;

  f32x4 acc[4][4];
  const f32x4 zero = {0.f, 0.f, 0.f, 0.f};
#pragma unroll
  for (int i = 0; i < 4; ++i)
#pragma unroll
    for (int j = 0; j < 4; ++j) acc[i][j] = zero;

  for (int kk = 0; kk < K; kk += 64) {
#pragma unroll
    for (int r = 0; r < 4; ++r) {
      const int id = tid + r * 256;
      const int row = id >> 3, ch = id & 7;
      *(u16x8*)&As[row][ch * 8] =
          *(const u16x8*)&A[(size_t)(m0 + row) * K + kk + ch * 8];
      *(u16x8*)&Bs[row][ch * 8] =
          *(const u16x8*)&Bw[(size_t)(n0 + row) * K + kk + ch * 8];
    }
    __syncthreads();
#pragma unroll
    for (int ks = 0; ks < 2; ++ks) {
      bx8 af[4], bf[4];
#pragma unroll
      for (int mf = 0; mf < 4; ++mf)
        af[mf] = *(const bx8*)&As[wr * 64 + mf * 16 + lr][ks * 32 + lhi * 8];
#pragma unroll
      for (int nf = 0; nf < 4; ++nf)
        bf[nf] = *(const bx8*)&Bs[wc * 64 + nf * 16 + lr][ks * 32 + lhi * 8];
#pragma unroll
      for (int mf = 0; mf < 4; ++mf)
#pragma unroll
        for (int nf = 0; nf < 4; ++nf)
          acc[mf][nf] = mfma16(af[mf], bf[nf], acc[mf][nf]);
    }
    __syncthreads();
  }
#pragma unroll
  for (int mf = 0; mf < 4; ++mf)
#pragma unroll
    for (int nf = 0; nf < 4; ++nf)
#pragma unroll
      for (int r = 0; r < 4; ++r) {
        const int row = m0 + wr * 64 + mf * 16 + lhi * 4 + r;
        const int col = n0 + wc * 64 + nf * 16 + lr;
        if constexpr (OUT_BF16)
          ((u16*)Cv)[(size_t)row * N + col] = f32_bf16(acc[mf][nf][r]);
        else
          ((float*)Cv)[(size_t)row * N + col] = acc[mf][nf][r];
      }
}

// ---------------------------------------------------------------- flash attn
// One block per (q-tile of 64, b*h). 4 waves; wave w owns q rows [w*16,w*16+16).
// K staged row-major, V staged transposed, online softmax in registers.
__global__ void __launch_bounds__(256) flash_attn(
    const u16* __restrict__ Qg, const u16* __restrict__ Kg,
    const u16* __restrict__ Vg, u16* __restrict__ Og) {
  constexpr int LDKS = 200;  // 16B slot = (25r+c)%8 = (r+c)%8 uniform
  constexpr int LDVT = 72;
  __shared__ u16 Ks[64][LDKS];
  __shared__ u16 Vt[CDH][LDVT];
  __shared__ u16 Ps[4][16][LDVT];
  const int qt = blockIdx.x;
  const int bh = blockIdx.y;
  const int b = bh >> 2, h = bh & 3;  // CH == 4
  const int tid = threadIdx.x;
  const int wave = tid >> 6, lane = tid & 63;
  const int lr = lane & 15, lhi = lane >> 4;
  const int q0 = qt * 64;
  const size_t rowbase = (size_t)b * CS;

  // Q fragments hoisted into registers (A-operand: row = lane&15)
  bx8 qf[6];
  {
    const size_t qoff = (rowbase + q0 + wave * 16 + lr) * CD + h * CDH;
#pragma unroll
    for (int c = 0; c < 6; ++c)
      qf[c] = *(const bx8*)&Qg[qoff + c * 32 + (size_t)lhi * 8];
  }

  float m_run[4], l_run[4];
  f32x4 acc_o[12];
  const f32x4 zero = {0.f, 0.f, 0.f, 0.f};
#pragma unroll
  for (int r = 0; r < 4; ++r) {
    m_run[r] = -INFINITY;
    l_run[r] = 0.f;
  }
#pragma unroll
  for (int nf = 0; nf < 12; ++nf) acc_o[nf] = zero;

  constexpr float scale = 0.07216878364870323f;  // 1/sqrt(192)

  for (int kt = 0; kt <= qt; ++kt) {
    const int k0 = kt * 64;
    // stage K row-major: ids cover 64 rows x 24 chunks of 8
#pragma unroll
    for (int r = 0; r < 6; ++r) {
      const unsigned id = tid + r * 256;
      const unsigned row = id / 24u, ch = id % 24u;
      *(u16x8*)&Ks[row][ch * 8] =
          *(const u16x8*)&Kg[(rowbase + k0 + row) * CD + h * CDH + ch * 8];
    }
    // stage V transposed: lane-contiguous k, 8 d-elems per load
#pragma unroll
    for (int r = 0; r < 6; ++r) {
      const unsigned id = tid + r * 256;
      const unsigned k = id & 63u, c = id >> 6;
      u16x8 v = *(const u16x8*)&Vg[(rowbase + k0 + k) * CD + h * CDH + c * 8];
#pragma unroll
      for (int j = 0; j < 8; ++j) Vt[c * 8 + j][k] = v[j];
    }
    __syncthreads();

    // S = Q K^T  (16 q-rows x 64 k-cols per wave)
    f32x4 sf[4];
#pragma unroll
    for (int nf = 0; nf < 4; ++nf) sf[nf] = zero;
#pragma unroll
    for (int c = 0; c < 6; ++c)
#pragma unroll
      for (int nf = 0; nf < 4; ++nf) {
        const bx8 kf = *(const bx8*)&Ks[nf * 16 + lr][c * 32 + lhi * 8];
        sf[nf] = mfma16(qf[c], kf, sf[nf]);
      }

    // scale + causal mask (diagonal tile only)
    float p[4][4];
    const bool diag = (kt == qt);
#pragma unroll
    for (int nf = 0; nf < 4; ++nf)
#pragma unroll
      for (int r = 0; r < 4; ++r) {
        float sv = sf[nf][r] * scale;
        if (diag && (nf * 16 + lr > wave * 16 + lhi * 4 + r)) sv = -INFINITY;
        p[nf][r] = sv;
      }

    // online softmax: row r lives at C-row (lhi*4+r); reduce over 16 lanes
    float mnew[4], alpha[4];
#pragma unroll
    for (int r = 0; r < 4; ++r) {
      float mx = fmaxf(fmaxf(p[0][r], p[1][r]), fmaxf(p[2][r], p[3][r]));
#pragma unroll
      for (int off = 1; off < 16; off <<= 1)
        mx = fmaxf(mx, __shfl_xor(mx, off, 64));
      mnew[r] = fmaxf(m_run[r], mx);
      alpha[r] = __expf(m_run[r] - mnew[r]);
      m_run[r] = mnew[r];
    }
#pragma unroll
    for (int r = 0; r < 4; ++r) {
      float rs = 0.f;
#pragma unroll
      for (int nf = 0; nf < 4; ++nf) {
        p[nf][r] = __expf(p[nf][r] - mnew[r]);
        rs += p[nf][r];
      }
#pragma unroll
      for (int off = 1; off < 16; off <<= 1) rs += __shfl_xor(rs, off, 64);
      l_run[r] = l_run[r] * alpha[r] + rs;
    }
#pragma unroll
    for (int nf = 0; nf < 12; ++nf)
#pragma unroll
      for (int r = 0; r < 4; ++r) acc_o[nf][r] *= alpha[r];

    // P: C-layout -> A-layout via per-wave LDS roundtrip
#pragma unroll
    for (int nf = 0; nf < 4; ++nf)
#pragma unroll
      for (int r = 0; r < 4; ++r)
        Ps[wave][lhi * 4 + r][nf * 16 + lr] = f32_bf16(p[nf][r]);
    const bx8 pf0 = *(const bx8*)&Ps[wave][lr][lhi * 8];
    const bx8 pf1 = *(const bx8*)&Ps[wave][lr][32 + lhi * 8];
    // O += P V
#pragma unroll
    for (int nf = 0; nf < 12; ++nf) {
      const bx8 vf0 = *(const bx8*)&Vt[nf * 16 + lr][lhi * 8];
      const bx8 vf1 = *(const bx8*)&Vt[nf * 16 + lr][32 + lhi * 8];
      acc_o[nf] = mfma16(pf0, vf0, acc_o[nf]);
      acc_o[nf] = mfma16(pf1, vf1, acc_o[nf]);
    }
    __syncthreads();
  }

  // epilogue: normalize and write preout in [B,S,D] layout
#pragma unroll
  for (int r = 0; r < 4; ++r) {
    const float inv = 1.0f / l_run[r];
    const size_t orow = (rowbase + q0 + wave * 16 + lhi * 4 + r) * CD + h * CDH;
#pragma unroll
    for (int nf = 0; nf < 12; ++nf)
      Og[orow + nf * 16 + lr] = f32_bf16(acc_o[nf][r] * inv);
  }
}

// ---------------------------------------------------------------- launch
extern "C" void kernel_launch(void* const* d_in, const int* in_sizes, int n_in,
                              void* d_out, int out_size, void* d_ws,
                              size_t ws_size, hipStream_t stream) {
  (void)in_sizes;
  (void)n_in;
  (void)out_size;
  (void)ws_size;
  const float* x = (const float*)d_in[0];
  const float* wq = (const float*)d_in[1];
  const float* wk = (const float*)d_in[2];
  const float* wv = (const float*)d_in[3];
  const float* wo = (const float*)d_in[4];
  float* out = (float*)d_out;
  char* ws = (char*)d_ws;
  const size_t big = (size_t)CM * CD * 2;  // 12,582,912 B
  const size_t wsz = (size_t)CD * CD * 2;  // 1,179,648 B
  u16* xb = (u16*)ws;  // reused as preout after QKV gemm
  u16* qb = (u16*)(ws + big);
  u16* kb = (u16*)(ws + 2 * big);
  u16* vb = (u16*)(ws + 3 * big);
  u16* wqb = (u16*)(ws + 4 * big);
  u16* wkb = (u16*)(ws + 4 * big + wsz);
  u16* wvb = (u16*)(ws + 4 * big + 2 * wsz);
  u16* wob = (u16*)(ws + 4 * big + 3 * wsz);
  u16* pob = xb;

  convert_all<<<dim3(1024), dim3(256), 0, stream>>>(x, wq, wk, wv, wo, xb, wqb,
                                                    wkb, wvb, wob);
  gemm_bt<true><<<dim3(64, 6, 3), dim3(256), 0, stream>>>(
      xb, wqb, wkb, wvb, (void*)qb, (void*)kb, (void*)vb, CM, CD, CD);
  flash_attn<<<dim3(32, 16), dim3(256), 0, stream>>>(qb, kb, vb, pob);
  gemm_bt<false><<<dim3(64, 6, 1), dim3(256), 0, stream>>>(
      pob, wob, wob, wob, (void*)out, (void*)out, (void*)out, CM, CD, CD);
}

// Round 3
// 172.122 us; speedup vs baseline: 2.2794x; 2.2794x over previous
//
#include <hip/hip_runtime.h>
#include <hip/hip_bf16.h>

// Shapes (fixed by the problem)
constexpr int CB = 4, CS = 2048, CD = 768, CH = 4, CDH = 192;
constexpr int CM = CB * CS;  // 8192 rows

typedef float f32x4 __attribute__((ext_vector_type(4)));
typedef float fx4 __attribute__((ext_vector_type(4)));
typedef __bf16 bx8 __attribute__((ext_vector_type(8)));
typedef unsigned short u16;
typedef u16 u16x8 __attribute__((ext_vector_type(8)));
typedef u16 u16x4 __attribute__((ext_vector_type(4)));

static __device__ __forceinline__ u16 f32_bf16(float f) {
  unsigned u = __builtin_bit_cast(unsigned, f);
  u += 0x7FFFu + ((u >> 16) & 1u);
  return (u16)(u >> 16);
}

static __device__ __forceinline__ f32x4 mfma16(bx8 a, bx8 b, f32x4 c) {
  return __builtin_amdgcn_mfma_f32_16x16x32_bf16(a, b, c, 0, 0, 0);
}

static __device__ __forceinline__ void load_lds16(const u16* g, u16* l) {
  __builtin_amdgcn_global_load_lds(
      (const __attribute__((address_space(1))) unsigned int*)g,
      (__attribute__((address_space(3))) unsigned int*)l, 16, 0, 0);
}

// ---------------------------------------------------------------- convert
__global__ void __launch_bounds__(256) convert_all(
    const float* __restrict__ x, const float* __restrict__ wq,
    const float* __restrict__ wk, const float* __restrict__ wv,
    const float* __restrict__ wo, u16* __restrict__ xb, u16* __restrict__ wqb,
    u16* __restrict__ wkb, u16* __restrict__ wvb, u16* __restrict__ wob) {
  const float* srcs[5] = {x, wq, wk, wv, wo};
  u16* dsts[5] = {xb, wqb, wkb, wvb, wob};
  const int n4s[5] = {CM * CD / 4, CD * CD / 4, CD * CD / 4, CD * CD / 4,
                      CD * CD / 4};
  const int gsz = gridDim.x * blockDim.x;
  const int gid = blockIdx.x * blockDim.x + threadIdx.x;
#pragma unroll
  for (int sg = 0; sg < 5; ++sg) {
    const fx4* src = (const fx4*)srcs[sg];
    u16* dst = dsts[sg];
    const int n4 = n4s[sg];
    for (int i = gid; i < n4; i += gsz) {
      fx4 v = src[i];
      u16x4 o;
      o[0] = f32_bf16(v[0]);
      o[1] = f32_bf16(v[1]);
      o[2] = f32_bf16(v[2]);
      o[3] = f32_bf16(v[3]);
      *(u16x4*)&dst[(size_t)i * 4] = o;
    }
  }
}

// ---------------------------------------------------------------- GEMM
// C[M,N] = A[M,K] @ B[N,K]^T ; A,B bf16 row-major. 128x128 tile, BK=64,
// 4 waves in 2x2, each wave 64x64 = 4x4 frags of 16x16x32.
template <bool OUT_BF16>
__global__ void __launch_bounds__(256) gemm_bt(
    const u16* __restrict__ A, const u16* __restrict__ Bw0,
    const u16* __restrict__ Bw1, const u16* __restrict__ Bw2,
    void* __restrict__ C0, void* __restrict__ C1, void* __restrict__ C2,
    int M, int N, int K) {
  constexpr int LDK = 72;  // padded: 16B slot = (9*row+c)%8 -> uniform
  __shared__ u16 As[128][LDK];
  __shared__ u16 Bs[128][LDK];
  const int z = blockIdx.z;
  const u16* Bw = (z == 0) ? Bw0 : ((z == 1) ? Bw1 : Bw2);
  void* Cv = (z == 0) ? C0 : ((z == 1) ? C1 : C2);
  const int m0 = blockIdx.x * 128;
  const int n0 = blockIdx.y * 128;
  const int tid = threadIdx.x;
  const int wave = tid >> 6, lane = tid & 63;
  const int wr = wave >> 1, wc = wave & 1;
  const int lr = lane & 15, lhi = lane >> 4;

  f32x4 acc[4][4];
  const f32x4 zero = {0.f, 0.f, 0.f, 0.f};
#pragma unroll
  for (int i = 0; i < 4; ++i)
#pragma unroll
    for (int j = 0; j < 4; ++j) acc[i][j] = zero;

  for (int kk = 0; kk < K; kk += 64) {
#pragma unroll
    for (int r = 0; r < 4; ++r) {
      const int id = tid + r * 256;
      const int row = id >> 3, ch = id & 7;
      *(u16x8*)&As[row][ch * 8] =
          *(const u16x8*)&A[(size_t)(m0 + row) * K + kk + ch * 8];
      *(u16x8*)&Bs[row][ch * 8] =
          *(const u16x8*)&Bw[(size_t)(n0 + row) * K + kk + ch * 8];
    }
    __syncthreads();
#pragma unroll
    for (int ks = 0; ks < 2; ++ks) {
      bx8 af[4], bf[4];
#pragma unroll
      for (int mf = 0; mf < 4; ++mf)
        af[mf] = *(const bx8*)&As[wr * 64 + mf * 16 + lr][ks * 32 + lhi * 8];
#pragma unroll
      for (int nf = 0; nf < 4; ++nf)
        bf[nf] = *(const bx8*)&Bs[wc * 64 + nf * 16 + lr][ks * 32 + lhi * 8];
#pragma unroll
      for (int mf = 0; mf < 4; ++mf)
#pragma unroll
        for (int nf = 0; nf < 4; ++nf)
          acc[mf][nf] = mfma16(af[mf], bf[nf], acc[mf][nf]);
    }
    __syncthreads();
  }
#pragma unroll
  for (int mf = 0; mf < 4; ++mf)
#pragma unroll
    for (int nf = 0; nf < 4; ++nf)
#pragma unroll
      for (int r = 0; r < 4; ++r) {
        const int row = m0 + wr * 64 + mf * 16 + lhi * 4 + r;
        const int col = n0 + wc * 64 + nf * 16 + lr;
        if constexpr (OUT_BF16)
          ((u16*)Cv)[(size_t)row * N + col] = f32_bf16(acc[mf][nf][r]);
        else
          ((float*)Cv)[(size_t)row * N + col] = acc[mf][nf][r];
      }
}

// ---------------------------------------------------------------- flash attn
// 256 blocks: block (pr, bh) handles q-tiles qt=pr and qt=31-pr (64 rows each)
// => 33 KV-tiles per block, perfectly balanced, 1 block/CU.
// 4 waves; wave w owns q rows [w*16, w*16+16).
// K: LDS linear [64][192] with XOR swizzle (byte ^= (k&7)<<4 within row),
//    staged via global_load_lds with inverse-swizzled global source.
// V: LDS subtiled 4k x 16d blocks: byte = ((d>>4)*16 + (k>>2))*128 +
//    (k&3)*32 + (d&15)*2, staged via global_load_lds, consumed via
//    ds_read_b64_tr_b16 (HW transpose read): per-lane addr =
//    subtile_base + (lane&15)*8 bytes; lane gets column (lane&15), rows j=0..3.
// QK^T swapped: S^T = mfma(K, Q) so each lane (lr=q) holds 16 k-values ->
// softmax reduce = in-lane tree + 2 shfl_xor.
__global__ void __launch_bounds__(256, 1) flash_attn(
    const u16* __restrict__ Qg, const u16* __restrict__ Kg,
    const u16* __restrict__ Vg, u16* __restrict__ Og) {
  __shared__ u16 Ks[2][12288];
  __shared__ u16 Vs[2][12288];
  __shared__ u16 Ps[4][16][72];
  const int pr = blockIdx.x;  // 0..15
  const int bh = blockIdx.y;
  const int b = bh >> 2, h = bh & 3;
  const int tid = threadIdx.x;
  const int wave = tid >> 6, lane = tid & 63;
  const int lr = lane & 15, lhi = lane >> 4;
  const size_t base_elem = ((size_t)b * CS) * CD + (size_t)h * CDH;
  constexpr float scale = 0.07216878364870323f;  // 1/sqrt(192)
  const f32x4 zero = {0.f, 0.f, 0.f, 0.f};

  // per-thread staging offsets (within a KV tile), elements
  int kOff[6], vOff[6];
#pragma unroll
  for (int r = 0; r < 6; ++r) {
    const int p = tid + r * 256;
    {
      const int k = p / 24, c16 = p - k * 24;
      const unsigned swz = ((unsigned)(c16 * 16)) ^ ((unsigned)((k & 7) << 4));
      kOff[r] = k * CD + (int)(swz >> 1);
    }
    {
      const int blk = p >> 3, kq = (p >> 1) & 3, dh = p & 1;
      const int kk = ((blk & 15) << 2) + kq;
      const int d = ((blk >> 4) << 4) + dh * 8;
      vOff[r] = kk * CD + d;
    }
  }
  const unsigned vlds0 =
      (unsigned)(unsigned long long)(__attribute__((address_space(3)))
                                         u16*)&Vs[0][0];

  const int qtA = pr, qtB = 31 - pr;
  float m_run = -INFINITY, l_run = 0.f;
  f32x4 acc[12];
#pragma unroll
  for (int nf = 0; nf < 12; ++nf) acc[nf] = zero;
  bx8 qf[6];

  auto qload = [&](int qt) {
    const size_t qoff = base_elem + (size_t)(qt * 64 + wave * 16 + lr) * CD;
#pragma unroll
    for (int c = 0; c < 6; ++c)
      qf[c] = *(const bx8*)&Qg[qoff + c * 32 + lhi * 8];
  };

  auto stage = [&](int buf, int kt) {
    const u16* kg = Kg + base_elem + (size_t)(kt * 64) * CD;
    const u16* vg = Vg + base_elem + (size_t)(kt * 64) * CD;
    u16* kd = &Ks[buf][0];
    u16* vd = &Vs[buf][0];
#pragma unroll
    for (int r = 0; r < 6; ++r)
      load_lds16(kg + kOff[r], kd + (size_t)(tid + r * 256) * 8);
#pragma unroll
    for (int r = 0; r < 6; ++r)
      load_lds16(vg + vOff[r], vd + (size_t)(tid + r * 256) * 8);
  };

  auto epilogue = [&](int qte) {
#pragma unroll
    for (int r = 0; r < 4; ++r) {
      const float lb = __shfl(l_run, lhi * 4 + r, 64);
      const float linv = 1.0f / lb;
      const size_t orow =
          base_elem + (size_t)(qte * 64 + wave * 16 + lhi * 4 + r) * CD;
#pragma unroll
      for (int nf = 0; nf < 12; ++nf)
        Og[orow + nf * 16 + lr] = f32_bf16(acc[nf][r] * linv);
    }
  };

  auto compute = [&](int bufc, int qtc, int ktc) {
    const u16* ksb = &Ks[bufc][0];
    const int qg = qtc * 64 + wave * 16 + lr;
    const int k0 = ktc * 64;
    // S^T = K Q^T : m = k rows, n = q cols
    f32x4 st[4];
#pragma unroll
    for (int mf = 0; mf < 4; ++mf) st[mf] = zero;
#pragma unroll
    for (int c = 0; c < 6; ++c)
#pragma unroll
      for (int mf = 0; mf < 4; ++mf) {
        const int row = mf * 16 + lr;
        const unsigned off =
            ((unsigned)(c * 64 + lhi * 16)) ^ ((unsigned)((row & 7) << 4));
        const bx8 kf = *(const bx8*)((const char*)ksb + (size_t)row * 384 + off);
        st[mf] = mfma16(kf, qf[c], st[mf]);
      }
    // scale + causal mask; lane lr holds q = qg, k = k0 + mf*16 + lhi*4 + r
    float pvv[16];
#pragma unroll
    for (int mf = 0; mf < 4; ++mf)
#pragma unroll
      for (int r = 0; r < 4; ++r) {
        float s = st[mf][r] * scale;
        if (k0 + mf * 16 + lhi * 4 + r > qg) s = -INFINITY;
        pvv[mf * 4 + r] = s;
      }
    // online softmax: in-lane over 16, then across lhi groups
    float mx = pvv[0];
#pragma unroll
    for (int t = 1; t < 16; ++t) mx = fmaxf(mx, pvv[t]);
    mx = fmaxf(mx, __shfl_xor(mx, 16, 64));
    mx = fmaxf(mx, __shfl_xor(mx, 32, 64));
    const float mnew = fmaxf(m_run, mx);
    const float alpha = __expf(m_run - mnew);
    float rs = 0.f;
#pragma unroll
    for (int t = 0; t < 16; ++t) {
      const float e = __expf(pvv[t] - mnew);
      pvv[t] = e;
      rs += e;
    }
    rs += __shfl_xor(rs, 16, 64);
    rs += __shfl_xor(rs, 32, 64);
    l_run = l_run * alpha + rs;
    m_run = mnew;
    // rescale O: acc row r is q_local = lhi*4 + r; alpha lives at lane q_local
    float afr[4];
#pragma unroll
    for (int r = 0; r < 4; ++r) afr[r] = __shfl(alpha, lhi * 4 + r, 64);
#pragma unroll
    for (int nf = 0; nf < 12; ++nf)
#pragma unroll
      for (int r = 0; r < 4; ++r) acc[nf][r] *= afr[r];
    // P^T (lane-local) -> Ps[q][k], packed u32 writes
#pragma unroll
    for (int mf = 0; mf < 4; ++mf)
#pragma unroll
      for (int rp = 0; rp < 2; ++rp) {
        const unsigned w0 = f32_bf16(pvv[mf * 4 + rp * 2]);
        const unsigned w1 = f32_bf16(pvv[mf * 4 + rp * 2 + 1]);
        *(unsigned*)&Ps[wave][lr][mf * 16 + lhi * 4 + rp * 2] =
            w0 | (w1 << 16);
      }
    const bx8 pf0 = *(const bx8*)&Ps[wave][lr][lhi * 8];
    const bx8 pf1 = *(const bx8*)&Ps[wave][lr][32 + lhi * 8];
    // O += P V via HW transpose reads of subtiled V.
    // Per-lane address: group (lhi) subtile base + lr*8 bytes; each lane
    // fetches 8B, HW transposes within the 16-lane group -> lane lr gets
    // column lr (d = nf*16+lr), rows j = 4 consecutive k.
    const unsigned vb = vlds0 + (unsigned)bufc * 24576u;
#pragma unroll
    for (int g = 0; g < 3; ++g) {
      u16x4 tl[4][2], th[4][2];
#pragma unroll
      for (int q4 = 0; q4 < 4; ++q4)
#pragma unroll
        for (int c2 = 0; c2 < 2; ++c2) {
          const int nf = g * 4 + q4;
          const unsigned va =
              vb + (unsigned)((nf * 16 + c2 * 8 + lhi * 2) * 128 + lr * 8);
          asm volatile("ds_read_b64_tr_b16 %0, %2\n\t"
                       "ds_read_b64_tr_b16 %1, %2 offset:128"
                       : "=&v"(tl[q4][c2]), "=&v"(th[q4][c2])
                       : "v"(va));
        }
      asm volatile("s_waitcnt lgkmcnt(0)" ::: "memory");
      __builtin_amdgcn_sched_barrier(0);
#pragma unroll
      for (int q4 = 0; q4 < 4; ++q4)
#pragma unroll
        for (int c2 = 0; c2 < 2; ++c2) {
          const int nf = g * 4 + q4;
          const u16x8 vv = __builtin_shufflevector(tl[q4][c2], th[q4][c2], 0,
                                                   1, 2, 3, 4, 5, 6, 7);
          acc[nf] = mfma16(c2 == 0 ? pf0 : pf1, __builtin_bit_cast(bx8, vv),
                           acc[nf]);
        }
    }
  };

  // pipeline: 33 tiles total (qtA: pr+1 tiles, then qtB: 32-pr tiles)
  stage(0, 0);
  qload(qtA);
  __syncthreads();
  int buf = 0;
  for (int i = 0; i < 33; ++i) {
    const int nxt = i + 1;
    if (nxt < 33) {
      const int k2 = (nxt <= pr) ? nxt : (nxt - pr - 1);
      stage(buf ^ 1, k2);
    }
    if (i == pr + 1) {
      epilogue(qtA);
      qload(qtB);
      m_run = -INFINITY;
      l_run = 0.f;
#pragma unroll
      for (int nf = 0; nf < 12; ++nf) acc[nf] = zero;
    }
    const int qcur = (i <= pr) ? qtA : qtB;
    const int kcur = (i <= pr) ? i : (i - pr - 1);
    compute(buf, qcur, kcur);
    __syncthreads();
    buf ^= 1;
  }
  epilogue(qtB);
}

// ---------------------------------------------------------------- launch
extern "C" void kernel_launch(void* const* d_in, const int* in_sizes, int n_in,
                              void* d_out, int out_size, void* d_ws,
                              size_t ws_size, hipStream_t stream) {
  (void)in_sizes;
  (void)n_in;
  (void)out_size;
  (void)ws_size;
  const float* x = (const float*)d_in[0];
  const float* wq = (const float*)d_in[1];
  const float* wk = (const float*)d_in[2];
  const float* wv = (const float*)d_in[3];
  const float* wo = (const float*)d_in[4];
  float* out = (float*)d_out;
  char* ws = (char*)d_ws;
  const size_t big = (size_t)CM * CD * 2;  // 12,582,912 B
  const size_t wsz = (size_t)CD * CD * 2;  // 1,179,648 B
  u16* xb = (u16*)ws;  // reused as preout after QKV gemm
  u16* qb = (u16*)(ws + big);
  u16* kb = (u16*)(ws + 2 * big);
  u16* vb = (u16*)(ws + 3 * big);
  u16* wqb = (u16*)(ws + 4 * big);
  u16* wkb = (u16*)(ws + 4 * big + wsz);
  u16* wvb = (u16*)(ws + 4 * big + 2 * wsz);
  u16* wob = (u16*)(ws + 4 * big + 3 * wsz);
  u16* pob = xb;

  convert_all<<<dim3(1024), dim3(256), 0, stream>>>(x, wq, wk, wv, wo, xb, wqb,
                                                    wkb, wvb, wob);
  gemm_bt<true><<<dim3(64, 6, 3), dim3(256), 0, stream>>>(
      xb, wqb, wkb, wvb, (void*)qb, (void*)kb, (void*)vb, CM, CD, CD);
  flash_attn<<<dim3(16, 16), dim3(256), 0, stream>>>(qb, kb, vb, pob);
  gemm_bt<false><<<dim3(64, 6, 1), dim3(256), 0, stream>>>(
      pob, wob, wob, wob, (void*)out, (void*)out, (void*)out, CM, CD, CD);
}

// Round 4
// 158.932 us; speedup vs baseline: 2.4686x; 1.0830x over previous
//
#include <hip/hip_runtime.h>
#include <hip/hip_bf16.h>

// Shapes (fixed by the problem)
constexpr int CB = 4, CS = 2048, CD = 768, CH = 4, CDH = 192;
constexpr int CM = CB * CS;  // 8192 rows

typedef float f32x4 __attribute__((ext_vector_type(4)));
typedef float fx4 __attribute__((ext_vector_type(4)));
typedef __bf16 bx8 __attribute__((ext_vector_type(8)));
typedef unsigned short u16;
typedef u16 u16x8 __attribute__((ext_vector_type(8)));
typedef u16 u16x4 __attribute__((ext_vector_type(4)));

static __device__ __forceinline__ u16 f32_bf16(float f) {
  unsigned u = __builtin_bit_cast(unsigned, f);
  u += 0x7FFFu + ((u >> 16) & 1u);
  return (u16)(u >> 16);
}

static __device__ __forceinline__ f32x4 mfma16(bx8 a, bx8 b, f32x4 c) {
  return __builtin_amdgcn_mfma_f32_16x16x32_bf16(a, b, c, 0, 0, 0);
}

// ---------------------------------------------------------------- convert
__global__ void __launch_bounds__(256) convert_all(
    const float* __restrict__ x, const float* __restrict__ wq,
    const float* __restrict__ wk, const float* __restrict__ wv,
    const float* __restrict__ wo, u16* __restrict__ xb, u16* __restrict__ wqb,
    u16* __restrict__ wkb, u16* __restrict__ wvb, u16* __restrict__ wob) {
  const float* srcs[5] = {x, wq, wk, wv, wo};
  u16* dsts[5] = {xb, wqb, wkb, wvb, wob};
  const int n4s[5] = {CM * CD / 4, CD * CD / 4, CD * CD / 4, CD * CD / 4,
                      CD * CD / 4};
  const int gsz = gridDim.x * blockDim.x;
  const int gid = blockIdx.x * blockDim.x + threadIdx.x;
#pragma unroll
  for (int sg = 0; sg < 5; ++sg) {
    const fx4* src = (const fx4*)srcs[sg];
    u16* dst = dsts[sg];
    const int n4 = n4s[sg];
    for (int i = gid; i < n4; i += gsz) {
      fx4 v = src[i];
      u16x4 o;
      o[0] = f32_bf16(v[0]);
      o[1] = f32_bf16(v[1]);
      o[2] = f32_bf16(v[2]);
      o[3] = f32_bf16(v[3]);
      *(u16x4*)&dst[(size_t)i * 4] = o;
    }
  }
}

// ---------------------------------------------------------------- GEMM
// C[M,N] = A[M,K] @ B[N,K]^T ; A,B bf16 row-major. 128x128 tile, BK=64,
// 4 waves in 2x2, each wave 64x64 = 4x4 frags of 16x16x32.
template <bool OUT_BF16>
__global__ void __launch_bounds__(256) gemm_bt(
    const u16* __restrict__ A, const u16* __restrict__ Bw0,
    const u16* __restrict__ Bw1, const u16* __restrict__ Bw2,
    void* __restrict__ C0, void* __restrict__ C1, void* __restrict__ C2,
    int M, int N, int K) {
  constexpr int LDK = 72;  // padded: 16B slot = (9*row+c)%8 -> uniform
  __shared__ u16 As[128][LDK];
  __shared__ u16 Bs[128][LDK];
  const int z = blockIdx.z;
  const u16* Bw = (z == 0) ? Bw0 : ((z == 1) ? Bw1 : Bw2);
  void* Cv = (z == 0) ? C0 : ((z == 1) ? C1 : C2);
  const int m0 = blockIdx.x * 128;
  const int n0 = blockIdx.y * 128;
  const int tid = threadIdx.x;
  const int wave = tid >> 6, lane = tid & 63;
  const int wr = wave >> 1, wc = wave & 1;
  const int lr = lane & 15, lhi = lane >> 4;

  f32x4 acc[4][4];
  const f32x4 zero = {0.f, 0.f, 0.f, 0.f};
#pragma unroll
  for (int i = 0; i < 4; ++i)
#pragma unroll
    for (int j = 0; j < 4; ++j) acc[i][j] = zero;

  for (int kk = 0; kk < K; kk += 64) {
#pragma unroll
    for (int r = 0; r < 4; ++r) {
      const int id = tid + r * 256;
      const int row = id >> 3, ch = id & 7;
      *(u16x8*)&As[row][ch * 8] =
          *(const u16x8*)&A[(size_t)(m0 + row) * K + kk + ch * 8];
      *(u16x8*)&Bs[row][ch * 8] =
          *(const u16x8*)&Bw[(size_t)(n0 + row) * K + kk + ch * 8];
    }
    __syncthreads();
#pragma unroll
    for (int ks = 0; ks < 2; ++ks) {
      bx8 af[4], bf[4];
#pragma unroll
      for (int mf = 0; mf < 4; ++mf)
        af[mf] = *(const bx8*)&As[wr * 64 + mf * 16 + lr][ks * 32 + lhi * 8];
#pragma unroll
      for (int nf = 0; nf < 4; ++nf)
        bf[nf] = *(const bx8*)&Bs[wc * 64 + nf * 16 + lr][ks * 32 + lhi * 8];
#pragma unroll
      for (int mf = 0; mf < 4; ++mf)
#pragma unroll
        for (int nf = 0; nf < 4; ++nf)
          acc[mf][nf] = mfma16(af[mf], bf[nf], acc[mf][nf]);
    }
    __syncthreads();
  }
#pragma unroll
  for (int mf = 0; mf < 4; ++mf)
#pragma unroll
    for (int nf = 0; nf < 4; ++nf)
#pragma unroll
      for (int r = 0; r < 4; ++r) {
        const int row = m0 + wr * 64 + mf * 16 + lhi * 4 + r;
        const int col = n0 + wc * 64 + nf * 16 + lr;
        if constexpr (OUT_BF16)
          ((u16*)Cv)[(size_t)row * N + col] = f32_bf16(acc[mf][nf][r]);
        else
          ((float*)Cv)[(size_t)row * N + col] = acc[mf][nf][r];
      }
}

// ---------------------------------------------------------------- flash attn
// 512 blocks (2 per CU): block g -> q-tile qt, bh. Ordering pairs block c with
// c+256 so their qt sums to 31 (co-resident CU load = 33 KV-tiles).
// 4 waves; wave w owns q rows [w*16, w*16+16).
// K: LDS linear [64][192] with XOR swizzle (byte ^= (k&7)<<4 within row),
//    reg-staged from inverse-swizzled global source.
// V: LDS subtiled 4k x 16d blocks, reg-staged, consumed via ds_read_b64_tr_b16
//    (per-lane addr = subtile_base + (lane&15)*8 bytes).
// QK^T swapped: S^T = mfma(K, Q); softmax reduce = in-lane tree + 2 shfl_xor.
// T14: global loads for tile i+1 issued right after LDS writes of tile i.
// T13: defer-max (THR=8) skips the O-rescale when the running max holds.
__global__ void __launch_bounds__(256, 2) flash_attn(
    const u16* __restrict__ Qg, const u16* __restrict__ Kg,
    const u16* __restrict__ Vg, u16* __restrict__ Og) {
  __shared__ u16 Ks[12288];
  __shared__ u16 Vs[12288];
  __shared__ u16 Ps[4][16][72];
  const int g = blockIdx.x;
  const int qt = (g < 256) ? (g >> 4) : (31 - ((g - 256) >> 4));
  const int bh = g & 15;
  const int b = bh >> 2, h = bh & 3;
  const int tid = threadIdx.x;
  const int wave = tid >> 6, lane = tid & 63;
  const int lr = lane & 15, lhi = lane >> 4;
  const size_t base_elem = ((size_t)b * CS) * CD + (size_t)h * CDH;
  constexpr float scale = 0.07216878364870323f;  // 1/sqrt(192)
  const f32x4 zero = {0.f, 0.f, 0.f, 0.f};

  // per-thread staging offsets (within a KV tile), elements
  int kOff[6], vOff[6];
#pragma unroll
  for (int r = 0; r < 6; ++r) {
    const int p = tid + r * 256;
    {
      const int k = p / 24, c16 = p - k * 24;
      const unsigned swz = ((unsigned)(c16 * 16)) ^ ((unsigned)((k & 7) << 4));
      kOff[r] = k * CD + (int)(swz >> 1);
    }
    {
      const int blk = p >> 3, kq = (p >> 1) & 3, dh = p & 1;
      const int kk = ((blk & 15) << 2) + kq;
      const int d = ((blk >> 4) << 4) + dh * 8;
      vOff[r] = kk * CD + d;
    }
  }
  const unsigned vlds0 =
      (unsigned)(unsigned long long)(__attribute__((address_space(3)))
                                         u16*)&Vs[0];

  float m_run = -INFINITY, l_run = 0.f;
  f32x4 acc[12];
#pragma unroll
  for (int nf = 0; nf < 12; ++nf) acc[nf] = zero;

  // Q fragments hoisted into registers (B-operand of swapped QK^T)
  bx8 qf[6];
  {
    const size_t qoff = base_elem + (size_t)(qt * 64 + wave * 16 + lr) * CD;
#pragma unroll
    for (int c = 0; c < 6; ++c)
      qf[c] = *(const bx8*)&Qg[qoff + c * 32 + lhi * 8];
  }

  u16x8 kreg[6], vreg[6];
  auto ldregs = [&](int kt) {
    const u16* kg = Kg + base_elem + (size_t)(kt * 64) * CD;
    const u16* vg = Vg + base_elem + (size_t)(kt * 64) * CD;
#pragma unroll
    for (int r = 0; r < 6; ++r) {
      kreg[r] = *(const u16x8*)&kg[kOff[r]];
      vreg[r] = *(const u16x8*)&vg[vOff[r]];
    }
  };

  ldregs(0);
  const int qg = qt * 64 + wave * 16 + lr;

  for (int i = 0; i <= qt; ++i) {
    __syncthreads();  // all waves done reading LDS tile i-1
#pragma unroll
    for (int r = 0; r < 6; ++r) {
      *(u16x8*)&Ks[(size_t)(tid + r * 256) * 8] = kreg[r];
      *(u16x8*)&Vs[(size_t)(tid + r * 256) * 8] = vreg[r];
    }
    if (i < qt) ldregs(i + 1);  // fly under compute(i)
    __syncthreads();  // writes visible

    // ---- compute tile i ----
    const int k0 = i * 64;
    const bool diag = (i == qt);
    // S^T = K Q^T : m = k rows, n = q cols
    f32x4 st[4];
#pragma unroll
    for (int mf = 0; mf < 4; ++mf) st[mf] = zero;
#pragma unroll
    for (int c = 0; c < 6; ++c)
#pragma unroll
      for (int mf = 0; mf < 4; ++mf) {
        const int row = mf * 16 + lr;
        const unsigned off =
            ((unsigned)(c * 64 + lhi * 16)) ^ ((unsigned)((row & 7) << 4));
        const bx8 kf =
            *(const bx8*)((const char*)Ks + (size_t)row * 384 + off);
        st[mf] = mfma16(kf, qf[c], st[mf]);
      }
    // scale + causal mask; lane lr holds q = qg, k = k0 + mf*16 + lhi*4 + r
    float pvv[16];
#pragma unroll
    for (int mf = 0; mf < 4; ++mf)
#pragma unroll
      for (int r = 0; r < 4; ++r) {
        float s = st[mf][r] * scale;
        if (diag && (k0 + mf * 16 + lhi * 4 + r > qg)) s = -INFINITY;
        pvv[mf * 4 + r] = s;
      }
    // online softmax: in-lane over 16, then across lhi groups
    float mx = pvv[0];
#pragma unroll
    for (int t = 1; t < 16; ++t) mx = fmaxf(mx, pvv[t]);
    mx = fmaxf(mx, __shfl_xor(mx, 16, 64));
    mx = fmaxf(mx, __shfl_xor(mx, 32, 64));
    // T13 defer-max: keep old m when growth <= 8 (P bounded by e^8, f32 ok)
    const bool skip = __all(mx - m_run <= 8.0f);
    if (!skip) {
      const float mnew = fmaxf(m_run, mx);
      const float alpha = __expf(m_run - mnew);
      float afr[4];
#pragma unroll
      for (int r = 0; r < 4; ++r) afr[r] = __shfl(alpha, lhi * 4 + r, 64);
#pragma unroll
      for (int nf = 0; nf < 12; ++nf)
#pragma unroll
        for (int r = 0; r < 4; ++r) acc[nf][r] *= afr[r];
      l_run *= alpha;
      m_run = mnew;
    }
    float rs = 0.f;
#pragma unroll
    for (int t = 0; t < 16; ++t) {
      const float e = __expf(pvv[t] - m_run);
      pvv[t] = e;
      rs += e;
    }
    rs += __shfl_xor(rs, 16, 64);
    rs += __shfl_xor(rs, 32, 64);
    l_run += rs;
    // P^T (lane-local) -> Ps[q][k], packed u32 writes
#pragma unroll
    for (int mf = 0; mf < 4; ++mf)
#pragma unroll
      for (int rp = 0; rp < 2; ++rp) {
        const unsigned w0 = f32_bf16(pvv[mf * 4 + rp * 2]);
        const unsigned w1 = f32_bf16(pvv[mf * 4 + rp * 2 + 1]);
        *(unsigned*)&Ps[wave][lr][mf * 16 + lhi * 4 + rp * 2] =
            w0 | (w1 << 16);
      }
    const bx8 pf0 = *(const bx8*)&Ps[wave][lr][lhi * 8];
    const bx8 pf1 = *(const bx8*)&Ps[wave][lr][32 + lhi * 8];
    // O += P V via HW transpose reads of subtiled V.
#pragma unroll
    for (int gg = 0; gg < 3; ++gg) {
      u16x4 tl[4][2], th[4][2];
#pragma unroll
      for (int q4 = 0; q4 < 4; ++q4)
#pragma unroll
        for (int c2 = 0; c2 < 2; ++c2) {
          const int nf = gg * 4 + q4;
          const unsigned va =
              vlds0 + (unsigned)((nf * 16 + c2 * 8 + lhi * 2) * 128 + lr * 8);
          asm volatile("ds_read_b64_tr_b16 %0, %2\n\t"
                       "ds_read_b64_tr_b16 %1, %2 offset:128"
                       : "=&v"(tl[q4][c2]), "=&v"(th[q4][c2])
                       : "v"(va));
        }
      asm volatile("s_waitcnt lgkmcnt(0)" ::: "memory");
      __builtin_amdgcn_sched_barrier(0);
#pragma unroll
      for (int q4 = 0; q4 < 4; ++q4)
#pragma unroll
        for (int c2 = 0; c2 < 2; ++c2) {
          const int nf = gg * 4 + q4;
          const u16x8 vv = __builtin_shufflevector(tl[q4][c2], th[q4][c2], 0,
                                                   1, 2, 3, 4, 5, 6, 7);
          acc[nf] = mfma16(c2 == 0 ? pf0 : pf1, __builtin_bit_cast(bx8, vv),
                           acc[nf]);
        }
    }
  }

  // epilogue: normalize and write preout in [B,S,D] layout
#pragma unroll
  for (int r = 0; r < 4; ++r) {
    const float lb = __shfl(l_run, lhi * 4 + r, 64);
    const float linv = 1.0f / lb;
    const size_t orow =
        base_elem + (size_t)(qt * 64 + wave * 16 + lhi * 4 + r) * CD;
#pragma unroll
    for (int nf = 0; nf < 12; ++nf)
      Og[orow + nf * 16 + lr] = f32_bf16(acc[nf][r] * linv);
  }
}

// ---------------------------------------------------------------- launch
extern "C" void kernel_launch(void* const* d_in, const int* in_sizes, int n_in,
                              void* d_out, int out_size, void* d_ws,
                              size_t ws_size, hipStream_t stream) {
  (void)in_sizes;
  (void)n_in;
  (void)out_size;
  (void)ws_size;
  const float* x = (const float*)d_in[0];
  const float* wq = (const float*)d_in[1];
  const float* wk = (const float*)d_in[2];
  const float* wv = (const float*)d_in[3];
  const float* wo = (const float*)d_in[4];
  float* out = (float*)d_out;
  char* ws = (char*)d_ws;
  const size_t big = (size_t)CM * CD * 2;  // 12,582,912 B
  const size_t wsz = (size_t)CD * CD * 2;  // 1,179,648 B
  u16* xb = (u16*)ws;  // reused as preout after QKV gemm
  u16* qb = (u16*)(ws + big);
  u16* kb = (u16*)(ws + 2 * big);
  u16* vb = (u16*)(ws + 3 * big);
  u16* wqb = (u16*)(ws + 4 * big);
  u16* wkb = (u16*)(ws + 4 * big + wsz);
  u16* wvb = (u16*)(ws + 4 * big + 2 * wsz);
  u16* wob = (u16*)(ws + 4 * big + 3 * wsz);
  u16* pob = xb;

  convert_all<<<dim3(1024), dim3(256), 0, stream>>>(x, wq, wk, wv, wo, xb, wqb,
                                                    wkb, wvb, wob);
  gemm_bt<true><<<dim3(64, 6, 3), dim3(256), 0, stream>>>(
      xb, wqb, wkb, wvb, (void*)qb, (void*)kb, (void*)vb, CM, CD, CD);
  flash_attn<<<dim3(512), dim3(256), 0, stream>>>(qb, kb, vb, pob);
  gemm_bt<false><<<dim3(64, 6, 1), dim3(256), 0, stream>>>(
      pob, wob, wob, wob, (void*)out, (void*)out, (void*)out, CM, CD, CD);
}